// Round 3
// baseline (9.746 us; speedup 1.0000x reference)
//
#include <hip/hip_runtime.h>

// Problem constants (match reference)
#define N_LOCS_C 500000
#define NN 100          // NUM_NEAREST
#define KK 16           // K
#define LL 8192         // L

// Two threads per output element (i,j): lane-pair splits the 100-element
// searchsorted scan and the two final gathers. Branch-free throughout.
__global__ __launch_bounds__(256)
void knn_pop_sampler_kernel(const int*   __restrict__ trg_seq,   // [L,2]
                            const float* __restrict__ u,         // [L,K]
                            const int*   __restrict__ nearby,    // [N_LOCS,NN]
                            const float* __restrict__ freqs,     // [N_LOCS,NN]
                            const float* __restrict__ cum,       // [N_LOCS,NN]
                            float*       __restrict__ out_samples, // [L,K]
                            float*       __restrict__ out_probs)   // [L,K]
{
    int tt = blockIdx.x * blockDim.x + threadIdx.x;  // 0 .. 2*L*K-1
    int p  = tt >> 1;        // output element id (i*K + j)
    int h  = tt & 1;         // which half of the pair
    int i  = p >> 4;         // K = 16

    int loc = trg_seq[2 * i + 1] - 1;
    loc = min(max(loc, 0), N_LOCS_C - 1);
    long long rowbase = (long long)loc * NN;

    float x = u[p];

    // Branch-free gather-table select for this lane: h=0 -> nearby, h=1 -> freqs
    const float* gtab = h ? freqs : (const float*)(const void*)nearby;

    // Speculative 1-line prefetch of the gather target: idx ~= x*NN since the
    // cum row is near-linear (log-weights are tightly distributed).
    int g = (int)(x * (float)NN);
    g = min(max(g, 0), NN - 1);
    float pf = gtab[rowbase + g];
    asm volatile("" :: "v"(pf));   // keep live, no output effect

    // ---- split bisect_left: count elements < x (row ascending) ----
    // h=0 covers elems [0,48) + [48,52); h=1 covers [52,100). Uniform control
    // flow: both run 12 quads from start=h*52, then both load the quad at 48
    // (same line -> broadcast) and only h=0 counts it.
    const float* crow = cum + rowbase;
    int start = h * 52;
    int cnt = 0;
#pragma unroll
    for (int q = 0; q < 48; q += 4) {
        float4 v = *reinterpret_cast<const float4*>(crow + start + q);
        cnt += (v.x < x) + (v.y < x) + (v.z < x) + (v.w < x);
    }
    {
        float4 v = *reinterpret_cast<const float4*>(crow + 48);
        int extra = (v.x < x) + (v.y < x) + (v.z < x) + (v.w < x);
        cnt += h ? 0 : extra;
    }
    cnt += __shfl_xor(cnt, 1);     // pair partner is lane^1 (same wave)
    int idx = min(cnt, NN - 1);

    // ---- split gather + store (one load, one store per thread) ----
    float raw = gtab[rowbase + idx];
    float val = h ? raw : (float)__float_as_int(raw);  // nearby is int32 bits
    float* optr = h ? out_probs : out_samples;
    optr[p] = val;
}

extern "C" void kernel_launch(void* const* d_in, const int* in_sizes, int n_in,
                              void* d_out, int out_size, void* d_ws, size_t ws_size,
                              hipStream_t stream) {
    const int*   trg_seq = (const int*)  d_in[0];   // [L,2] int32
    // d_in[1] is k == 16 (compile-time constant here)
    const float* u       = (const float*)d_in[2];   // [L,K] f32
    const int*   nearby  = (const int*)  d_in[3];   // [N_LOCS,NN] int32
    const float* freqs   = (const float*)d_in[4];   // [N_LOCS,NN] f32
    const float* cum     = (const float*)d_in[5];   // [N_LOCS,NN] f32

    float* out = (float*)d_out;
    float* out_samples = out;            // first L*K
    float* out_probs   = out + LL * KK;  // second L*K

    const int total  = 2 * LL * KK;      // 262144 threads (2 per element)
    const int block  = 256;
    const int grid   = (total + block - 1) / block;  // 1024
    knn_pop_sampler_kernel<<<grid, block, 0, stream>>>(
        trg_seq, u, nearby, freqs, cum, out_samples, out_probs);
}